// Round 10
// baseline (435.923 us; speedup 1.0000x reference)
//
#include <hip/hip_runtime.h>
#include <math.h>

#define N_NODES 50000
#define N_EDGES 800000
#define G_GRAPHS 64
#define CONV_BLOCKS 2048
#define BSTRIDE 64    // epk bucket stride per node (max degree; Poisson(16) tail ~1e-13)
#define NCB 196       // coarse buckets: dst>>8, 49999>>8 = 195
#define CCAP 1280     // capacity per (coarse bucket, sub) — mean ~1020, +8 sigma

#define WAVE_SYNC() asm volatile("s_waitcnt lgkmcnt(0)" ::: "memory")
#define RFL(v) __builtin_amdgcn_readfirstlane(v)

// ---- mlp1 (+ zeroing + enc/encm setup in block 0) + fused u(layer 0) ----
__global__ void k_mlp1(const float* __restrict__ x,
                       const float* __restrict__ w1, const float* __restrict__ b1,
                       const float* __restrict__ w2, const float* __restrict__ b2,
                       float* __restrict__ h,
                       int* __restrict__ bfill4,
                       float* __restrict__ bn_part, float* __restrict__ g,
                       float* __restrict__ avg_log,
                       const float* __restrict__ edge_emb,
                       const float* __restrict__ enc_w, const float* __restrict__ enc_b,
                       const float* __restrict__ pre_w, float* __restrict__ encm,
                       float* __restrict__ u) {
  __shared__ float eo[2][4][10];
  __shared__ float sw[500];   // layer-0 W_src: [t][k][f]
  int tid = threadIdx.x;
  int n = blockIdx.x * blockDim.x + tid;
  if (n < 1280) bn_part[n] = 0.f;          // [2][32][20]
  if (n < G_GRAPHS * 10) g[n] = 0.f;
  if (n < NCB * 4) bfill4[n] = 0;
  if (n == 0) avg_log[0] = 0.f;

  bool act = n < N_NODES;
  float hr[10];
  if (act) {
    float xv[10];
#pragma unroll
    for (int k = 0; k < 10; k++) xv[k] = x[n * 10 + k];
    float hid[5];
#pragma unroll
    for (int j = 0; j < 5; j++) {
      float a = b1[j];
#pragma unroll
      for (int k = 0; k < 10; k++) a += xv[k] * w1[k * 5 + j];
      hid[j] = fmaxf(a, 0.f);
    }
#pragma unroll
    for (int f = 0; f < 10; f++) {
      float a = b2[f];
#pragma unroll
      for (int j = 0; j < 5; j++) a += hid[j] * w2[j * 10 + f];
      hr[f] = a;
      h[n * 10 + f] = a;
    }
  }
  for (int j = tid; j < 500; j += 256) {
    int t = j / 100, k = (j / 10) % 10, f = j % 10;
    sw[j] = pre_w[(t * 30 + 10 + k) * 10 + f];
  }
  if (blockIdx.x == 0) {
    for (int i = tid; i < 80; i += 256) {
      int l = i / 40; int a = (i / 10) % 4; int k = i % 10;
      float s = enc_b[l * 10 + k];
      for (int j = 0; j < 10; j++) s += edge_emb[a * 10 + j] * enc_w[(l * 10 + j) * 10 + k];
      eo[l][a][k] = s;
    }
  }
  __syncthreads();
  if (blockIdx.x == 0) {
    for (int i = tid; i < 400; i += 256) {
      int l = i / 200; int a = (i / 50) % 4; int t = (i / 10) % 5; int f = i % 10;
      float s = 0.f;
      for (int k = 0; k < 10; k++) s += eo[l][a][k] * pre_w[((l * 5 + t) * 30 + 20 + k) * 10 + f];
      encm[i] = s;
    }
  }
  if (act) {
    float2* up = (float2*)(u + n * 50);
#pragma unroll
    for (int c0 = 0; c0 < 25; c0++) {
      int ca = 2 * c0, cb = 2 * c0 + 1;
      int ta = ca / 10, fa = ca % 10, tb = cb / 10, fb = cb % 10;
      float a = 0.f, b = 0.f;
#pragma unroll
      for (int k = 0; k < 10; k++) {
        a += hr[k] * sw[ta * 100 + fa + k * 10];
        b += hr[k] * sw[tb * 100 + fb + k * 10];
      }
      up[c0] = make_float2(a, b);
    }
  }
}

// ---- phase C: scatter edges into coarse dst-range buckets (dense-ish writes) ----
// rec = dst_lo(8) | src(16)<<8 | attr(2)<<24
__global__ void k_coarse(const int* __restrict__ src, const int* __restrict__ dst,
                         const int* __restrict__ attr,
                         int* __restrict__ bfill4, int* __restrict__ coarse) {
  int e = blockIdx.x * blockDim.x + threadIdx.x;
  if (e >= N_EDGES) return;
  int d = dst[e];
  int s = src[e];
  int a = attr[e];
  int cs = (d >> 8) * 4 + (e & 3);
  int k = atomicAdd(&bfill4[cs], 1);
  if (k < CCAP) coarse[cs * CCAP + k] = (d & 255) | (s << 8) | (a << 24);
}

// ---- phase D: one block per coarse bucket -> epk (XCD-local 64KB region), cnt, avg_log ----
__global__ __launch_bounds__(256) void k_fine(const int* __restrict__ bfill4,
                                              const int* __restrict__ coarse,
                                              int* __restrict__ epk,
                                              int* __restrict__ cnt,
                                              float* __restrict__ avg_log) {
  __shared__ int lcnt[256];
  __shared__ float wred[4];
  int tid = threadIdx.x;
  int b = blockIdx.x;
  int n0 = b * 256;
  lcnt[tid] = 0;
  __syncthreads();
#pragma unroll
  for (int s = 0; s < 4; s++) {
    int cs = b * 4 + s;
    int len = bfill4[cs];
    if (len > CCAP) len = CCAP;
    const int* base = coarse + cs * CCAP;
    for (int j = tid; j < len; j += 256) {
      int rec = base[j];
      int dlo = rec & 255;
      int k = atomicAdd(&lcnt[dlo], 1);
      if (k < BSTRIDE) epk[(n0 + dlo) * BSTRIDE + k] = rec >> 8;  // src | attr<<16
    }
  }
  __syncthreads();
  int deg = lcnt[tid];
  float lg = 0.f;
  if (n0 + tid < N_NODES) {
    cnt[n0 + tid] = deg;
    lg = __logf((float)deg + 1.f);
  }
#pragma unroll
  for (int d = 32; d >= 1; d >>= 1) lg += __shfl_down(lg, d, 64);
  if ((tid & 63) == 0) wred[tid >> 6] = lg;
  __syncthreads();
  if (tid == 0) atomicAdd(avg_log, wred[0] + wred[1] + wred[2] + wred[3]);
}

// ---- fused PNA conv: 8-deep pipelined f32 gathers of u[src] + next-node epk prefetch ----
__global__ __launch_bounds__(256) void k_conv(
    const float* __restrict__ h,         // [N][10]
    const float* __restrict__ u,         // [N][50]
    const float* __restrict__ pre_w_l,   // [5][30][10]
    const float* __restrict__ pre_b_l,   // [5][10]
    const float* __restrict__ post_w_l,  // [5][130][2]
    const float* __restrict__ post_b_l,  // [5][2]
    const float* __restrict__ lin_w_l,   // [10][10]
    const float* __restrict__ lin_b_l,   // [10]
    const float* __restrict__ encm_l,    // [4][5][10]
    const int* __restrict__ cnt,
    const int* __restrict__ epk,         // [N][BSTRIDE]
    const float* __restrict__ avg_log_p,
    float* __restrict__ o_buf,
    float* __restrict__ bn_part)         // [32][20]
{
  __shared__ float sW[1300];
  __shared__ float sLin[100];
  __shared__ float sLb[10];
  __shared__ float sPb[10];
  __shared__ float sP[4][100];
  __shared__ float sO[4][10];
  __shared__ float bnS[10], bnQ[10];

  int tid = threadIdx.x;
  int wid = tid >> 6, lane = tid & 63;
  for (int i = tid; i < 1300; i += 256) sW[i] = post_w_l[i];
  for (int i = tid; i < 100; i += 256) sLin[i] = lin_w_l[i];
  if (tid < 10) {
    sLb[tid] = lin_b_l[tid];
    sPb[tid] = post_b_l[tid];
    bnS[tid] = 0.f; bnQ[tid] = 0.f;
  }
  __syncthreads();

  int f = lane % 10;
  int t = (lane < 50) ? (lane / 10) : 4;
  int c50 = t * 10 + f;
  float wdst[10];
#pragma unroll
  for (int k = 0; k < 10; k++) wdst[k] = pre_w_l[(t * 30 + k) * 10 + f];
  float em0 = encm_l[c50];
  float em1 = encm_l[50 + c50];
  float em2 = encm_l[100 + c50];
  float em3 = encm_l[150 + c50];
  float preb = pre_b_l[c50];
  float avg_log = avg_log_p[0] * (1.f / N_NODES);

  int gw = blockIdx.x * 4 + wid;       // global wave id
  int GW = gridDim.x * 4;
  int nn = (gw < N_NODES) ? ((N_NODES - 1 - gw) / GW + 1) : 0;

  int dgp = 0;
  if (lane < nn) dgp = cnt[gw + lane * GW];

  float bnSv = 0.f, bnQv = 0.f;

#define PRE(US, AS, IDX) { int sp_ = __builtin_amdgcn_readlane(pk, (IDX) & 63); \
    AS = sp_ >> 16; US = 0.f; \
    if ((IDX) < deg) US = u[(sp_ & 0xFFFF) * 50 + c50]; }
#define PROC(US, AS) { float em_ = (AS & 2) ? ((AS & 1) ? em3 : em2) : ((AS & 1) ? em1 : em0); \
    float m_ = base + em_ + US; \
    sum += m_; sq = fmaf(m_, m_, sq); mnv = fminf(mnv, m_); mxv = fmaxf(mxv, m_); }

  // prefetch node 0's epk bucket
  int nxt_pk = 0;
  if (nn > 0) {
    int deg0 = RFL(__builtin_amdgcn_readlane(dgp, 0));
    if (deg0 > BSTRIDE) deg0 = BSTRIDE;
    if (lane < deg0) nxt_pk = epk[gw * BSTRIDE + lane];
  }

  for (int i = 0; i < nn; i++) {
    int n = gw + i * GW;
    int deg = RFL(__builtin_amdgcn_readlane(dgp, i));
    if (deg > BSTRIDE) deg = BSTRIDE;
    int pk = nxt_pk;
    // prefetch next node's bucket while we chew on this one
    if (i + 1 < nn) {
      int degN = RFL(__builtin_amdgcn_readlane(dgp, i + 1));
      if (degN > BSTRIDE) degN = BSTRIDE;
      int nN = gw + (i + 1) * GW;
      nxt_pk = (lane < degN) ? epk[nN * BSTRIDE + lane] : 0;
    }

    const float* hn = h + n * 10;            // uniform address
    float2 d0 = *(const float2*)hn;
    float2 d1 = *(const float2*)(hn + 2);
    float2 d2 = *(const float2*)(hn + 4);
    float2 d3 = *(const float2*)(hn + 6);
    float2 d4 = *(const float2*)(hn + 8);
    float xf = hn[f];
    float base = preb
      + d0.x * wdst[0] + d0.y * wdst[1] + d1.x * wdst[2] + d1.y * wdst[3]
      + d2.x * wdst[4] + d2.y * wdst[5] + d3.x * wdst[6] + d3.y * wdst[7]
      + d4.x * wdst[8] + d4.y * wdst[9];

    float sum = 0.f, sq = 0.f, mnv = INFINITY, mxv = -INFINITY;
    {
      float u0, u1, u2, u3, u4, u5, u6, u7;
      int a0, a1, a2, a3, a4, a5, a6, a7;
      PRE(u0, a0, 0) PRE(u1, a1, 1) PRE(u2, a2, 2) PRE(u3, a3, 3)
      PRE(u4, a4, 4) PRE(u5, a5, 5) PRE(u6, a6, 6) PRE(u7, a7, 7)
      int full = deg & ~7;
      int jb = 0;
      for (; jb < full; jb += 8) {
        PROC(u0, a0) PRE(u0, a0, jb + 8)
        PROC(u1, a1) PRE(u1, a1, jb + 9)
        PROC(u2, a2) PRE(u2, a2, jb + 10)
        PROC(u3, a3) PRE(u3, a3, jb + 11)
        PROC(u4, a4) PRE(u4, a4, jb + 12)
        PROC(u5, a5) PRE(u5, a5, jb + 13)
        PROC(u6, a6) PRE(u6, a6, jb + 14)
        PROC(u7, a7) PRE(u7, a7, jb + 15)
      }
      if (jb + 0 < deg) PROC(u0, a0)
      if (jb + 1 < deg) PROC(u1, a1)
      if (jb + 2 < deg) PROC(u2, a2)
      if (jb + 3 < deg) PROC(u3, a3)
      if (jb + 4 < deg) PROC(u4, a4)
      if (jb + 5 < deg) PROC(u5, a5)
      if (jb + 6 < deg) PROC(u6, a6)
    }

    float degf = (float)deg;
    float d = fmaxf(degf, 1.f);
    float inv = 1.f / d;
    float mean = sum * inv;
    float var = sq * inv - mean * mean;
    float stdv = sqrtf(fmaxf(var, 0.f) + 1e-5f);
    if (deg == 0) { mnv = 0.f; mxv = 0.f; }
    float log_d = logf(d + 1.f);
    float amp = log_d / avg_log;
    float att = avg_log / log_d;

    float vv[13];
    vv[0] = xf;
    vv[1] = mean;       vv[2] = mnv;        vv[3] = mxv;        vv[4] = stdv;
    vv[5] = mean * amp; vv[6] = mnv * amp;  vv[7] = mxv * amp;  vv[8] = stdv * amp;
    vv[9] = mean * att; vv[10] = mnv * att; vv[11] = mxv * att; vv[12] = stdv * att;
    float p0 = 0.f, p1 = 0.f;
#pragma unroll
    for (int j = 0; j < 13; j++) {
      const float2 w = *(const float2*)&sW[t * 260 + (f + 10 * j) * 2];
      p0 += vv[j] * w.x; p1 += vv[j] * w.y;
    }
    if (lane < 50) *(float2*)&sP[wid][c50 * 2] = make_float2(p0, p1);
    WAVE_SYNC();
    if (lane < 10) {
      int tt = lane >> 1, c = lane & 1;
      float o = sPb[lane];
#pragma unroll
      for (int ff = 0; ff < 10; ff++) o += sP[wid][(tt * 10 + ff) * 2 + c];
      sO[wid][lane] = o;
    }
    WAVE_SYNC();
    if (lane < 10) {
      float r = sLb[lane];
#pragma unroll
      for (int j = 0; j < 10; j++) r += sO[wid][j] * sLin[j * 10 + lane];
      o_buf[n * 10 + lane] = r;
      bnSv += r; bnQv += r * r;
    }
    WAVE_SYNC();
  }
#undef PRE
#undef PROC

  if (lane < 10) {
    atomicAdd(&bnS[lane], bnSv);
    atomicAdd(&bnQ[lane], bnQv);
  }
  __syncthreads();
  if (tid < 20) {
    float v = (tid < 10) ? bnS[tid] : bnQ[tid - 10];
    atomicAdd(&bn_part[(blockIdx.x & 31) * 20 + tid], v);
  }
}

// ---- BN (from 32 partials) + relu + fused u(next layer) OR pool. 25 nodes/block ----
__global__ __launch_bounds__(256) void k_bnpool(
    const float* __restrict__ o_buf,
    const float* __restrict__ bn_part,  // [32][20]
    const float* __restrict__ gamma, const float* __restrict__ beta,
    float* __restrict__ h,              // [N][10]
    const int* __restrict__ batch, float* __restrict__ g,
    const float* __restrict__ pre_w_next, float* __restrict__ u,
    int do_u, int do_pool) {
  __shared__ float sS[20];
  __shared__ float sMu[10], sInv[10];
  __shared__ float pool[8][10];
  __shared__ float hrow[25][10];
  __shared__ float sw[500];
  __shared__ int g0s;
  int tid = threadIdx.x;
  int n0 = blockIdx.x * 25;
  if (do_u) {
    for (int j = tid; j < 500; j += 256) {
      int t = j / 100, k = (j / 10) % 10, f = j % 10;
      sw[j] = pre_w_next[(t * 30 + 10 + k) * 10 + f];
    }
  }
  if (tid < 20) {
    float s = 0.f;
    for (int j = 0; j < 32; j++) s += bn_part[j * 20 + tid];
    sS[tid] = s;
  }
  if (tid < 80) pool[tid / 10][tid % 10] = 0.f;
  if (tid == 0) g0s = batch[n0];
  __syncthreads();
  if (tid < 10) {
    float mu = sS[tid] * (1.f / N_NODES);
    float var = sS[10 + tid] * (1.f / N_NODES) - mu * mu;
    sMu[tid] = mu;
    sInv[tid] = 1.f / sqrtf(fmaxf(var, 0.f) + 1e-5f);
  }
  __syncthreads();
  if (tid < 250) {
    int dn = tid / 10, f = tid % 10;
    int n = n0 + dn;
    int i = n * 10 + f;
    float o = (o_buf[i] - sMu[f]) * sInv[f] * gamma[f] + beta[f];
    float r = fmaxf(o, 0.f);
    h[i] = r;
    hrow[dn][f] = r;
    if (do_pool) {
      int dg = batch[n] - g0s;
      if (dg < 8) atomicAdd(&pool[dg][f], r);
      else atomicAdd(&g[(g0s + dg) * 10 + f], r);
    }
  }
  __syncthreads();
  if (do_u && tid < 250) {
#pragma unroll
    for (int it = 0; it < 5; it++) {
      int j = tid + it * 250;
      int node = j / 50, c = j % 50;
      int t = c / 10, f2 = c % 10;
      float acc = 0.f;
#pragma unroll
      for (int k = 0; k < 10; k++) acc += hrow[node][k] * sw[t * 100 + f2 + k * 10];
      u[n0 * 50 + j] = acc;
    }
  }
  if (do_pool) {
    __syncthreads();
    if (tid < 80) {
      float v = pool[tid / 10][tid % 10];
      if (v != 0.f) atomicAdd(&g[(g0s + tid / 10) * 10 + tid % 10], v);
    }
  }
}

// ---------------- mlp2 ----------------
__global__ void k_mlp2(const float* __restrict__ g,
                       const float* __restrict__ w1, const float* __restrict__ b1,
                       const float* __restrict__ w2, const float* __restrict__ b2,
                       float* __restrict__ out) {
  int b = threadIdx.x;
  if (b >= G_GRAPHS) return;
  float gv[10];
#pragma unroll
  for (int k = 0; k < 10; k++) gv[k] = g[b * 10 + k];
  float acc = b2[0];
#pragma unroll
  for (int j = 0; j < 5; j++) {
    float a = b1[j];
#pragma unroll
    for (int k = 0; k < 10; k++) a += gv[k] * w1[k * 5 + j];
    acc += fmaxf(a, 0.f) * w2[j];
  }
  out[b] = acc;
}

extern "C" void kernel_launch(void* const* d_in, const int* in_sizes, int n_in,
                              void* d_out, int out_size, void* d_ws, size_t ws_size,
                              hipStream_t stream) {
  const float* x        = (const float*)d_in[0];
  const float* edge_emb = (const float*)d_in[1];
  const float* m1w1 = (const float*)d_in[2];
  const float* m1b1 = (const float*)d_in[3];
  const float* m1w2 = (const float*)d_in[4];
  const float* m1b2 = (const float*)d_in[5];
  const float* enc_w = (const float*)d_in[6];
  const float* enc_b = (const float*)d_in[7];
  const float* pre_w = (const float*)d_in[8];
  const float* pre_b = (const float*)d_in[9];
  const float* post_w = (const float*)d_in[10];
  const float* post_b = (const float*)d_in[11];
  const float* lin_w = (const float*)d_in[12];
  const float* lin_b = (const float*)d_in[13];
  const float* bn_g = (const float*)d_in[14];
  const float* bn_b = (const float*)d_in[15];
  const float* m2w1 = (const float*)d_in[16];
  const float* m2b1 = (const float*)d_in[17];
  const float* m2w2 = (const float*)d_in[18];
  const float* m2b2 = (const float*)d_in[19];
  const int* edge_index = (const int*)d_in[20];
  const int* edge_attr  = (const int*)d_in[21];
  const int* batch      = (const int*)d_in[22];
  const int* src  = edge_index;
  const int* dstp = edge_index + N_EDGES;

  char* ws = (char*)d_ws;
  size_t off = 0;
  auto alloc = [&](size_t bytes) {
    void* p = ws + off;
    off += (bytes + 255) & ~(size_t)255;
    return p;
  };
  float*     h       = (float*)alloc(N_NODES * 10 * sizeof(float));
  float*     o_buf   = (float*)alloc(N_NODES * 10 * sizeof(float));
  float*     u       = (float*)alloc((size_t)(N_NODES * 50 + 64) * sizeof(float));
  int*       cnt     = (int*)alloc(N_NODES * sizeof(int));
  int*       epk     = (int*)alloc((size_t)N_NODES * BSTRIDE * sizeof(int));
  int*       bfill4  = (int*)alloc(NCB * 4 * sizeof(int));
  int*       coarse  = (int*)alloc((size_t)NCB * 4 * CCAP * sizeof(int));
  float*     encm    = (float*)alloc(400 * sizeof(float));
  float*     avg_log = (float*)alloc(16);
  float*     bn_part = (float*)alloc(2 * 32 * 20 * sizeof(float));
  float*     g       = (float*)alloc(G_GRAPHS * 10 * sizeof(float));

  k_mlp1<<<(N_NODES + 255) / 256, 256, 0, stream>>>(x, m1w1, m1b1, m1w2, m1b2, h,
                                                    bfill4, bn_part, g, avg_log,
                                                    edge_emb, enc_w, enc_b, pre_w, encm, u);
  k_coarse<<<(N_EDGES + 255) / 256, 256, 0, stream>>>(src, dstp, edge_attr, bfill4, coarse);
  k_fine<<<NCB, 256, 0, stream>>>(bfill4, coarse, epk, cnt, avg_log);

  for (int l = 0; l < 2; l++) {
    k_conv<<<CONV_BLOCKS, 256, 0, stream>>>(
        h, u, pre_w + l * 1500, pre_b + l * 50, post_w + l * 1300, post_b + l * 10,
        lin_w + l * 100, lin_b + l * 10, encm + l * 200,
        cnt, epk, avg_log, o_buf, bn_part + l * 640);
    k_bnpool<<<N_NODES / 25, 256, 0, stream>>>(
        o_buf, bn_part + l * 640, bn_g + l * 10, bn_b + l * 10, h, batch, g,
        pre_w + 1500, u, l == 0, l == 1);
  }
  k_mlp2<<<1, 64, 0, stream>>>(g, m2w1, m2b1, m2w2, m2b2, (float*)d_out);
}

// Round 11
// 285.737 us; speedup vs baseline: 1.5256x; 1.5256x over previous
//
#include <hip/hip_runtime.h>
#include <math.h>

#define N_NODES 50000
#define N_EDGES 800000
#define G_GRAPHS 64
#define CONV_BLOCKS 2048
#define BSTRIDE 64    // epk bucket stride per node (max degree; Poisson(16) tail ~1e-13)
#define CPAD 16       // cnt padded: one counter per 64B line

#define WAVE_SYNC() asm volatile("s_waitcnt lgkmcnt(0)" ::: "memory")
#define RFL(v) __builtin_amdgcn_readfirstlane(v)

// ---- mlp1 (+ zeroing + enc/encm setup in block 0) + fused u(layer 0) ----
__global__ void k_mlp1(const float* __restrict__ x,
                       const float* __restrict__ w1, const float* __restrict__ b1,
                       const float* __restrict__ w2, const float* __restrict__ b2,
                       float* __restrict__ h,
                       int* __restrict__ cnt,      // [N*CPAD]
                       float* __restrict__ bn_part, float* __restrict__ g,
                       float* __restrict__ avg_log,
                       const float* __restrict__ edge_emb,
                       const float* __restrict__ enc_w, const float* __restrict__ enc_b,
                       const float* __restrict__ pre_w, float* __restrict__ encm,
                       float* __restrict__ u) {
  __shared__ float eo[2][4][10];
  __shared__ float sw[500];   // layer-0 W_src: [t][k][f]
  int tid = threadIdx.x;
  int n = blockIdx.x * blockDim.x + tid;
  if (n < 1280) bn_part[n] = 0.f;          // [2][32][20]
  if (n < G_GRAPHS * 10) g[n] = 0.f;
  if (n == 0) avg_log[0] = 0.f;

  bool act = n < N_NODES;
  float hr[10];
  if (act) {
    cnt[n * CPAD] = 0;
    float xv[10];
#pragma unroll
    for (int k = 0; k < 10; k++) xv[k] = x[n * 10 + k];
    float hid[5];
#pragma unroll
    for (int j = 0; j < 5; j++) {
      float a = b1[j];
#pragma unroll
      for (int k = 0; k < 10; k++) a += xv[k] * w1[k * 5 + j];
      hid[j] = fmaxf(a, 0.f);
    }
#pragma unroll
    for (int f = 0; f < 10; f++) {
      float a = b2[f];
#pragma unroll
      for (int j = 0; j < 5; j++) a += hid[j] * w2[j * 10 + f];
      hr[f] = a;
      h[n * 10 + f] = a;
    }
  }
  for (int j = tid; j < 500; j += 256) {
    int t = j / 100, k = (j / 10) % 10, f = j % 10;
    sw[j] = pre_w[(t * 30 + 10 + k) * 10 + f];
  }
  if (blockIdx.x == 0) {
    for (int i = tid; i < 80; i += 256) {
      int l = i / 40; int a = (i / 10) % 4; int k = i % 10;
      float s = enc_b[l * 10 + k];
      for (int j = 0; j < 10; j++) s += edge_emb[a * 10 + j] * enc_w[(l * 10 + j) * 10 + k];
      eo[l][a][k] = s;
    }
  }
  __syncthreads();
  if (blockIdx.x == 0) {
    for (int i = tid; i < 400; i += 256) {
      int l = i / 200; int a = (i / 50) % 4; int t = (i / 10) % 5; int f = i % 10;
      float s = 0.f;
      for (int k = 0; k < 10; k++) s += eo[l][a][k] * pre_w[((l * 5 + t) * 30 + 20 + k) * 10 + f];
      encm[i] = s;
    }
  }
  if (act) {
    float2* up = (float2*)(u + n * 50);
#pragma unroll
    for (int c0 = 0; c0 < 25; c0++) {
      int ca = 2 * c0, cb = 2 * c0 + 1;
      int ta = ca / 10, fa = ca % 10, tb = cb / 10, fb = cb % 10;
      float a = 0.f, b = 0.f;
#pragma unroll
      for (int k = 0; k < 10; k++) {
        a += hr[k] * sw[ta * 100 + fa + k * 10];
        b += hr[k] * sw[tb * 100 + fb + k * 10];
      }
      up[c0] = make_float2(a, b);
    }
  }
}

// ---- single-pass count+scatter, 1 edge/thread; rank counters one-per-cache-line ----
__global__ void k_scatter(const int* __restrict__ src, const int* __restrict__ dst,
                          const int* __restrict__ attr,
                          int* __restrict__ cnt, int* __restrict__ epk) {
  int e = blockIdx.x * blockDim.x + threadIdx.x;
  if (e >= N_EDGES) return;
  int d = dst[e];
  int s = src[e];
  int a = attr[e];
  int k = atomicAdd(&cnt[d * CPAD], 1);
  if (k < BSTRIDE) epk[d * BSTRIDE + k] = s | (a << 16);
}

// ---- avg_log = sum_n log(deg_n + 1)  (conv divides by N) ----
__global__ void k_avg(const int* __restrict__ cnt, float* __restrict__ avg_log) {
  __shared__ float ws[4];
  int tid = threadIdx.x;
  float acc = 0.f;
  for (int n = blockIdx.x * 256 + tid; n < N_NODES; n += gridDim.x * 256)
    acc += __logf((float)cnt[n * CPAD] + 1.f);
#pragma unroll
  for (int d = 32; d >= 1; d >>= 1) acc += __shfl_down(acc, d, 64);
  if ((tid & 63) == 0) ws[tid >> 6] = acc;
  __syncthreads();
  if (tid == 0) atomicAdd(avg_log, ws[0] + ws[1] + ws[2] + ws[3]);
}

// ---- fused PNA conv: 8-deep pipelined f32 gathers of u[src] + next-node epk prefetch ----
__global__ __launch_bounds__(256) void k_conv(
    const float* __restrict__ h,         // [N][10]
    const float* __restrict__ u,         // [N][50]
    const float* __restrict__ pre_w_l,   // [5][30][10]
    const float* __restrict__ pre_b_l,   // [5][10]
    const float* __restrict__ post_w_l,  // [5][130][2]
    const float* __restrict__ post_b_l,  // [5][2]
    const float* __restrict__ lin_w_l,   // [10][10]
    const float* __restrict__ lin_b_l,   // [10]
    const float* __restrict__ encm_l,    // [4][5][10]
    const int* __restrict__ cnt,         // [N*CPAD]
    const int* __restrict__ epk,         // [N][BSTRIDE]
    const float* __restrict__ avg_log_p,
    float* __restrict__ o_buf,
    float* __restrict__ bn_part)         // [32][20]
{
  __shared__ float sW[1300];
  __shared__ float sLin[100];
  __shared__ float sLb[10];
  __shared__ float sPb[10];
  __shared__ float sP[4][100];
  __shared__ float sO[4][10];
  __shared__ float bnS[10], bnQ[10];

  int tid = threadIdx.x;
  int wid = tid >> 6, lane = tid & 63;
  for (int i = tid; i < 1300; i += 256) sW[i] = post_w_l[i];
  for (int i = tid; i < 100; i += 256) sLin[i] = lin_w_l[i];
  if (tid < 10) {
    sLb[tid] = lin_b_l[tid];
    sPb[tid] = post_b_l[tid];
    bnS[tid] = 0.f; bnQ[tid] = 0.f;
  }
  __syncthreads();

  int f = lane % 10;
  int t = (lane < 50) ? (lane / 10) : 4;
  int c50 = t * 10 + f;
  float wdst[10];
#pragma unroll
  for (int k = 0; k < 10; k++) wdst[k] = pre_w_l[(t * 30 + k) * 10 + f];
  float em0 = encm_l[c50];
  float em1 = encm_l[50 + c50];
  float em2 = encm_l[100 + c50];
  float em3 = encm_l[150 + c50];
  float preb = pre_b_l[c50];
  float avg_log = avg_log_p[0] * (1.f / N_NODES);

  int gw = blockIdx.x * 4 + wid;       // global wave id
  int GW = gridDim.x * 4;
  int nn = (gw < N_NODES) ? ((N_NODES - 1 - gw) / GW + 1) : 0;

  int dgp = 0;
  if (lane < nn) dgp = cnt[(gw + lane * GW) * CPAD];

  float bnSv = 0.f, bnQv = 0.f;

#define PRE(US, AS, IDX) { int sp_ = __builtin_amdgcn_readlane(pk, (IDX) & 63); \
    AS = sp_ >> 16; US = 0.f; \
    if ((IDX) < deg) US = u[(sp_ & 0xFFFF) * 50 + c50]; }
#define PROC(US, AS) { float em_ = (AS & 2) ? ((AS & 1) ? em3 : em2) : ((AS & 1) ? em1 : em0); \
    float m_ = base + em_ + US; \
    sum += m_; sq = fmaf(m_, m_, sq); mnv = fminf(mnv, m_); mxv = fmaxf(mxv, m_); }

  // prefetch node 0's epk bucket
  int nxt_pk = 0;
  if (nn > 0) {
    int deg0 = RFL(__builtin_amdgcn_readlane(dgp, 0));
    if (deg0 > BSTRIDE) deg0 = BSTRIDE;
    if (lane < deg0) nxt_pk = epk[gw * BSTRIDE + lane];
  }

  for (int i = 0; i < nn; i++) {
    int n = gw + i * GW;
    int deg = RFL(__builtin_amdgcn_readlane(dgp, i));
    if (deg > BSTRIDE) deg = BSTRIDE;
    int pk = nxt_pk;
    // prefetch next node's bucket while we chew on this one
    if (i + 1 < nn) {
      int degN = RFL(__builtin_amdgcn_readlane(dgp, i + 1));
      if (degN > BSTRIDE) degN = BSTRIDE;
      int nN = gw + (i + 1) * GW;
      nxt_pk = (lane < degN) ? epk[nN * BSTRIDE + lane] : 0;
    }

    const float* hn = h + n * 10;            // uniform address
    float2 d0 = *(const float2*)hn;
    float2 d1 = *(const float2*)(hn + 2);
    float2 d2 = *(const float2*)(hn + 4);
    float2 d3 = *(const float2*)(hn + 6);
    float2 d4 = *(const float2*)(hn + 8);
    float xf = hn[f];
    float base = preb
      + d0.x * wdst[0] + d0.y * wdst[1] + d1.x * wdst[2] + d1.y * wdst[3]
      + d2.x * wdst[4] + d2.y * wdst[5] + d3.x * wdst[6] + d3.y * wdst[7]
      + d4.x * wdst[8] + d4.y * wdst[9];

    float sum = 0.f, sq = 0.f, mnv = INFINITY, mxv = -INFINITY;
    {
      float u0, u1, u2, u3, u4, u5, u6, u7;
      int a0, a1, a2, a3, a4, a5, a6, a7;
      PRE(u0, a0, 0) PRE(u1, a1, 1) PRE(u2, a2, 2) PRE(u3, a3, 3)
      PRE(u4, a4, 4) PRE(u5, a5, 5) PRE(u6, a6, 6) PRE(u7, a7, 7)
      int full = deg & ~7;
      int jb = 0;
      for (; jb < full; jb += 8) {
        PROC(u0, a0) PRE(u0, a0, jb + 8)
        PROC(u1, a1) PRE(u1, a1, jb + 9)
        PROC(u2, a2) PRE(u2, a2, jb + 10)
        PROC(u3, a3) PRE(u3, a3, jb + 11)
        PROC(u4, a4) PRE(u4, a4, jb + 12)
        PROC(u5, a5) PRE(u5, a5, jb + 13)
        PROC(u6, a6) PRE(u6, a6, jb + 14)
        PROC(u7, a7) PRE(u7, a7, jb + 15)
      }
      if (jb + 0 < deg) PROC(u0, a0)
      if (jb + 1 < deg) PROC(u1, a1)
      if (jb + 2 < deg) PROC(u2, a2)
      if (jb + 3 < deg) PROC(u3, a3)
      if (jb + 4 < deg) PROC(u4, a4)
      if (jb + 5 < deg) PROC(u5, a5)
      if (jb + 6 < deg) PROC(u6, a6)
    }

    float degf = (float)deg;
    float d = fmaxf(degf, 1.f);
    float inv = 1.f / d;
    float mean = sum * inv;
    float var = sq * inv - mean * mean;
    float stdv = sqrtf(fmaxf(var, 0.f) + 1e-5f);
    if (deg == 0) { mnv = 0.f; mxv = 0.f; }
    float log_d = logf(d + 1.f);
    float amp = log_d / avg_log;
    float att = avg_log / log_d;

    float vv[13];
    vv[0] = xf;
    vv[1] = mean;       vv[2] = mnv;        vv[3] = mxv;        vv[4] = stdv;
    vv[5] = mean * amp; vv[6] = mnv * amp;  vv[7] = mxv * amp;  vv[8] = stdv * amp;
    vv[9] = mean * att; vv[10] = mnv * att; vv[11] = mxv * att; vv[12] = stdv * att;
    float p0 = 0.f, p1 = 0.f;
#pragma unroll
    for (int j = 0; j < 13; j++) {
      const float2 w = *(const float2*)&sW[t * 260 + (f + 10 * j) * 2];
      p0 += vv[j] * w.x; p1 += vv[j] * w.y;
    }
    if (lane < 50) *(float2*)&sP[wid][c50 * 2] = make_float2(p0, p1);
    WAVE_SYNC();
    if (lane < 10) {
      int tt = lane >> 1, c = lane & 1;
      float o = sPb[lane];
#pragma unroll
      for (int ff = 0; ff < 10; ff++) o += sP[wid][(tt * 10 + ff) * 2 + c];
      sO[wid][lane] = o;
    }
    WAVE_SYNC();
    if (lane < 10) {
      float r = sLb[lane];
#pragma unroll
      for (int j = 0; j < 10; j++) r += sO[wid][j] * sLin[j * 10 + lane];
      o_buf[n * 10 + lane] = r;
      bnSv += r; bnQv += r * r;
    }
    WAVE_SYNC();
  }
#undef PRE
#undef PROC

  if (lane < 10) {
    atomicAdd(&bnS[lane], bnSv);
    atomicAdd(&bnQ[lane], bnQv);
  }
  __syncthreads();
  if (tid < 20) {
    float v = (tid < 10) ? bnS[tid] : bnQ[tid - 10];
    atomicAdd(&bn_part[(blockIdx.x & 31) * 20 + tid], v);
  }
}

// ---- BN (from 32 partials) + relu + fused u(next layer) OR pool. 25 nodes/block ----
__global__ __launch_bounds__(256) void k_bnpool(
    const float* __restrict__ o_buf,
    const float* __restrict__ bn_part,  // [32][20]
    const float* __restrict__ gamma, const float* __restrict__ beta,
    float* __restrict__ h,              // [N][10]
    const int* __restrict__ batch, float* __restrict__ g,
    const float* __restrict__ pre_w_next, float* __restrict__ u,
    int do_u, int do_pool) {
  __shared__ float sS[20];
  __shared__ float sMu[10], sInv[10];
  __shared__ float pool[8][10];
  __shared__ float hrow[25][10];
  __shared__ float sw[500];
  __shared__ int g0s;
  int tid = threadIdx.x;
  int n0 = blockIdx.x * 25;
  if (do_u) {
    for (int j = tid; j < 500; j += 256) {
      int t = j / 100, k = (j / 10) % 10, f = j % 10;
      sw[j] = pre_w_next[(t * 30 + 10 + k) * 10 + f];
    }
  }
  if (tid < 20) {
    float s = 0.f;
    for (int j = 0; j < 32; j++) s += bn_part[j * 20 + tid];
    sS[tid] = s;
  }
  if (tid < 80) pool[tid / 10][tid % 10] = 0.f;
  if (tid == 0) g0s = batch[n0];
  __syncthreads();
  if (tid < 10) {
    float mu = sS[tid] * (1.f / N_NODES);
    float var = sS[10 + tid] * (1.f / N_NODES) - mu * mu;
    sMu[tid] = mu;
    sInv[tid] = 1.f / sqrtf(fmaxf(var, 0.f) + 1e-5f);
  }
  __syncthreads();
  if (tid < 250) {
    int dn = tid / 10, f = tid % 10;
    int n = n0 + dn;
    int i = n * 10 + f;
    float o = (o_buf[i] - sMu[f]) * sInv[f] * gamma[f] + beta[f];
    float r = fmaxf(o, 0.f);
    h[i] = r;
    hrow[dn][f] = r;
    if (do_pool) {
      int dg = batch[n] - g0s;
      if (dg < 8) atomicAdd(&pool[dg][f], r);
      else atomicAdd(&g[(g0s + dg) * 10 + f], r);
    }
  }
  __syncthreads();
  if (do_u && tid < 250) {
#pragma unroll
    for (int it = 0; it < 5; it++) {
      int j = tid + it * 250;
      int node = j / 50, c = j % 50;
      int t = c / 10, f2 = c % 10;
      float acc = 0.f;
#pragma unroll
      for (int k = 0; k < 10; k++) acc += hrow[node][k] * sw[t * 100 + f2 + k * 10];
      u[n0 * 50 + j] = acc;
    }
  }
  if (do_pool) {
    __syncthreads();
    if (tid < 80) {
      float v = pool[tid / 10][tid % 10];
      if (v != 0.f) atomicAdd(&g[(g0s + tid / 10) * 10 + tid % 10], v);
    }
  }
}

// ---------------- mlp2 ----------------
__global__ void k_mlp2(const float* __restrict__ g,
                       const float* __restrict__ w1, const float* __restrict__ b1,
                       const float* __restrict__ w2, const float* __restrict__ b2,
                       float* __restrict__ out) {
  int b = threadIdx.x;
  if (b >= G_GRAPHS) return;
  float gv[10];
#pragma unroll
  for (int k = 0; k < 10; k++) gv[k] = g[b * 10 + k];
  float acc = b2[0];
#pragma unroll
  for (int j = 0; j < 5; j++) {
    float a = b1[j];
#pragma unroll
    for (int k = 0; k < 10; k++) a += gv[k] * w1[k * 5 + j];
    acc += fmaxf(a, 0.f) * w2[j];
  }
  out[b] = acc;
}

extern "C" void kernel_launch(void* const* d_in, const int* in_sizes, int n_in,
                              void* d_out, int out_size, void* d_ws, size_t ws_size,
                              hipStream_t stream) {
  const float* x        = (const float*)d_in[0];
  const float* edge_emb = (const float*)d_in[1];
  const float* m1w1 = (const float*)d_in[2];
  const float* m1b1 = (const float*)d_in[3];
  const float* m1w2 = (const float*)d_in[4];
  const float* m1b2 = (const float*)d_in[5];
  const float* enc_w = (const float*)d_in[6];
  const float* enc_b = (const float*)d_in[7];
  const float* pre_w = (const float*)d_in[8];
  const float* pre_b = (const float*)d_in[9];
  const float* post_w = (const float*)d_in[10];
  const float* post_b = (const float*)d_in[11];
  const float* lin_w = (const float*)d_in[12];
  const float* lin_b = (const float*)d_in[13];
  const float* bn_g = (const float*)d_in[14];
  const float* bn_b = (const float*)d_in[15];
  const float* m2w1 = (const float*)d_in[16];
  const float* m2b1 = (const float*)d_in[17];
  const float* m2w2 = (const float*)d_in[18];
  const float* m2b2 = (const float*)d_in[19];
  const int* edge_index = (const int*)d_in[20];
  const int* edge_attr  = (const int*)d_in[21];
  const int* batch      = (const int*)d_in[22];
  const int* src  = edge_index;
  const int* dstp = edge_index + N_EDGES;

  char* ws = (char*)d_ws;
  size_t off = 0;
  auto alloc = [&](size_t bytes) {
    void* p = ws + off;
    off += (bytes + 255) & ~(size_t)255;
    return p;
  };
  float*     h       = (float*)alloc(N_NODES * 10 * sizeof(float));
  float*     o_buf   = (float*)alloc(N_NODES * 10 * sizeof(float));
  float*     u       = (float*)alloc((size_t)(N_NODES * 50 + 64) * sizeof(float));
  int*       cnt     = (int*)alloc((size_t)N_NODES * CPAD * sizeof(int));
  int*       epk     = (int*)alloc((size_t)N_NODES * BSTRIDE * sizeof(int));
  float*     encm    = (float*)alloc(400 * sizeof(float));
  float*     avg_log = (float*)alloc(16);
  float*     bn_part = (float*)alloc(2 * 32 * 20 * sizeof(float));
  float*     g       = (float*)alloc(G_GRAPHS * 10 * sizeof(float));

  k_mlp1<<<(N_NODES + 255) / 256, 256, 0, stream>>>(x, m1w1, m1b1, m1w2, m1b2, h,
                                                    cnt, bn_part, g, avg_log,
                                                    edge_emb, enc_w, enc_b, pre_w, encm, u);
  k_scatter<<<(N_EDGES + 255) / 256, 256, 0, stream>>>(src, dstp, edge_attr, cnt, epk);
  k_avg<<<64, 256, 0, stream>>>(cnt, avg_log);

  for (int l = 0; l < 2; l++) {
    k_conv<<<CONV_BLOCKS, 256, 0, stream>>>(
        h, u, pre_w + l * 1500, pre_b + l * 50, post_w + l * 1300, post_b + l * 10,
        lin_w + l * 100, lin_b + l * 10, encm + l * 200,
        cnt, epk, avg_log, o_buf, bn_part + l * 640);
    k_bnpool<<<N_NODES / 25, 256, 0, stream>>>(
        o_buf, bn_part + l * 640, bn_g + l * 10, bn_b + l * 10, h, batch, g,
        pre_w + 1500, u, l == 0, l == 1);
  }
  k_mlp2<<<1, 64, 0, stream>>>(g, m2w1, m2b1, m2w2, m2b2, (float*)d_out);
}